// Round 6
// baseline (632.817 us; speedup 1.0000x reference)
//
#include <hip/hip_runtime.h>
#include <hip/hip_bf16.h>
#include <math.h>
#include <stdint.h>

typedef __bf16 bf16_t;
typedef __attribute__((ext_vector_type(8))) __bf16 bf16x8;
typedef __attribute__((ext_vector_type(4))) float f32x4;
typedef unsigned short u16;
typedef unsigned int u32;

#define DEV static __device__ __forceinline__
#define LOG2E 1.4426950408889634f

DEV u16 f2b(float f){ bf16_t h = (bf16_t)f; return __builtin_bit_cast(u16, h); }
DEV float b2f(u16 u){ bf16_t h = __builtin_bit_cast(bf16_t, u); return (float)h; }
DEV f32x4 mfma16(bf16x8 a, bf16x8 b, f32x4 c){
  return __builtin_amdgcn_mfma_f32_16x16x32_bf16(a, b, c, 0, 0, 0);
}

#if __has_builtin(__builtin_amdgcn_exp2f)
DEV float fexp2(float x){ return __builtin_amdgcn_exp2f(x); }
#else
DEV float fexp2(float x){ return exp2f(x); }
#endif

DEV void gld16(const void* g, void* l){
  __builtin_amdgcn_global_load_lds((const __attribute__((address_space(1))) u32*)g,
                                   (__attribute__((address_space(3))) u32*)l, 16, 0, 0);
}

DEV bf16x8 ldsA32(const u16* arr, int row, int ch){
  return *(const bf16x8*)&arr[row*32 + ((ch ^ ((row>>1)&3))*8)];
}

// ---------------- converts ----------------
__global__ __launch_bounds__(256) void k_convert_x(const float* __restrict__ x,
                                                   u16* __restrict__ xh, u16* __restrict__ xl){
  size_t i = ((size_t)blockIdx.x*256 + threadIdx.x)*4;
  float4 v = *(const float4*)(x + i);
  ushort4 hv, lv; float f, hf;
  f=v.x; hv.x=f2b(f); hf=b2f(hv.x); lv.x=f2b(f-hf);
  f=v.y; hv.y=f2b(f); hf=b2f(hv.y); lv.y=f2b(f-hf);
  f=v.z; hv.z=f2b(f); hf=b2f(hv.z); lv.z=f2b(f-hf);
  f=v.w; hv.w=f2b(f); hf=b2f(hv.w); lv.w=f2b(f-hf);
  *(ushort4*)(xh+i) = hv;
  *(ushort4*)(xl+i) = lv;
}

// W [K][N] -> Wt [N][K] bf16 (hi only)
__global__ __launch_bounds__(256) void k_convert_w(const float* __restrict__ Wq, const float* __restrict__ Wk,
                                                   const float* __restrict__ Wv, const float* __restrict__ Wo,
                                                   u16* __restrict__ wth, u16* __restrict__ wot){
  __shared__ float tile[64][65];
  int z = blockIdx.z;
  const float* W = (z==0)?Wq:((z==1)?Wk:((z==2)?Wv:Wo));
  int n0 = blockIdx.x*64, k0 = blockIdx.y*64;
  int t = threadIdx.x;
  int r = t>>6, c = t&63;
  #pragma unroll
  for(int i=0;i<16;i++){
    int row = i*4 + r;
    tile[row][c] = W[(size_t)(k0+row)*1024 + n0 + c];
  }
  __syncthreads();
  #pragma unroll
  for(int i=0;i<16;i++){
    int nrow = i*4 + r;
    float v = tile[c][nrow];
    size_t o = (size_t)(n0+nrow)*1024 + k0 + c;
    if(z<3) wth[(size_t)z*1048576 + o] = f2b(v);
    else    wot[o] = f2b(v);
  }
}

// ---------------- bias tables ----------------
__global__ __launch_bounds__(256) void k_bias_table(const float* __restrict__ rel_table,
                                                    const float* __restrict__ mask,
                                                    float* __restrict__ bt, float* __restrict__ bt2,
                                                    float* __restrict__ msk2){
  int gid = blockIdx.x*256 + threadIdx.x;   // 16*4096
  if(gid < 4096) msk2[gid] = mask[gid]*LOG2E;
  int h = gid >> 12, idx = gid & 4095;
  float v = 0.f;
  if(idx < 4095){
    int delta = idx - 2047;   // k - q
    int n = -delta;
    int ret = 0;
    if(n < 0){ ret = 16; n = -n; }
    int bucket;
    if(n < 8) bucket = n + ret;
    else {
      float a = (float)log((double)n * 0.125);
      float rr = (float)((double)a / (double)2.7725887298583984f);
      int vl = 8 + (int)(rr * 8.0f);
      vl = vl > 15 ? 15 : vl;
      bucket = vl + ret;
    }
    v = rel_table[bucket*16 + h];
  }
  bt[gid] = v;
  bt2[gid] = v*LOG2E - 32.0f;
}

__global__ __launch_bounds__(256) void k_write_bias(const float* __restrict__ bt,
                                                    float* __restrict__ out){
  size_t f = ((size_t)blockIdx.x*256 + threadIdx.x)*4;
  int h = (int)(f >> 22);
  int rem = (int)(f & 4194303);
  int q = rem >> 11;
  int k = rem & 2047;
  const float* row = bt + h*4096 + (k - q + 2047);
  float4 v = make_float4(row[0], row[1], row[2], row[3]);
  *(float4*)(out + f) = v;
}

// ---------------- QKV projection GEMM (2-term: (xh+xl)*Wh) ----------------
__global__ __launch_bounds__(256) void k_gemm_qkv(const u16* __restrict__ xh, const u16* __restrict__ xl,
                                                  const u16* __restrict__ wth,
                                                  u16* __restrict__ qh, u16* __restrict__ ql,
                                                  u16* __restrict__ kh, u16* __restrict__ vt){
  __shared__ __align__(16) u16 SM[17408];
  u16* Ah = SM; u16* Al = SM+4096; u16* Bh = SM+8192;
  int z = blockIdx.z;
  const u16* WH = wth + (size_t)z*1048576;
  int m0 = blockIdx.y*128, n0 = blockIdx.x*128;
  int t = threadIdx.x, w = t>>6, lane = t&63, l16 = lane&15, g = lane>>4;
  f32x4 acc[4][4];
  #pragma unroll
  for(int i=0;i<4;i++)
    #pragma unroll
    for(int j=0;j<4;j++) acc[i][j] = {0.f,0.f,0.f,0.f};
  int rbase = (w>>1)*64, cbase = (w&1)*64;
  for(int k0=0;k0<1024;k0+=32){
    __syncthreads();
    #pragma unroll
    for(int jj=0;jj<6;jj++){
      int q = w + 4*jj;            // chunk id 0..23: Ah 0-7, Al 8-15, Bh 16-23
      int arr = q>>3, sub = q&7;
      if(z==2 && arr==1) continue;      // V: single-term, skip x-lo
      int row = sub*16 + (lane>>2);
      int lch = (lane&3) ^ ((row>>1)&3);
      const u16* src;
      if(arr==0)      src = xh + (size_t)(m0+row)*1024 + k0 + lch*8;
      else if(arr==1) src = xl + (size_t)(m0+row)*1024 + k0 + lch*8;
      else            src = WH + (size_t)(n0+row)*1024 + k0 + lch*8;
      gld16(src, &SM[q*512]);
    }
    __syncthreads();
    if(z==2){
      bf16x8 ah[4];
      #pragma unroll
      for(int i=0;i<4;i++) ah[i] = ldsA32(Ah, rbase + i*16 + l16, g);
      #pragma unroll
      for(int j=0;j<4;j++){
        bf16x8 bh = ldsA32(Bh, cbase + j*16 + l16, g);
        #pragma unroll
        for(int i=0;i<4;i++)
          acc[i][j] = mfma16(ah[i], bh, acc[i][j]);
      }
    } else {
      bf16x8 ah[4], am[4];
      #pragma unroll
      for(int i=0;i<4;i++){
        int row = rbase + i*16 + l16;
        ah[i] = ldsA32(Ah, row, g);
        am[i] = ldsA32(Al, row, g);
      }
      #pragma unroll
      for(int j=0;j<4;j++){
        bf16x8 bh = ldsA32(Bh, cbase + j*16 + l16, g);
        #pragma unroll
        for(int i=0;i<4;i++){
          acc[i][j] = mfma16(ah[i], bh, acc[i][j]);
          acc[i][j] = mfma16(am[i], bh, acc[i][j]);
        }
      }
    }
  }
  if(z==2){
    // V: transpose via LDS (stride 136), coalesced 16B stores; vt [bh][d][s]
    __syncthreads();
    #pragma unroll
    for(int i=0;i<4;i++)
      #pragma unroll
      for(int j=0;j<4;j++)
        #pragma unroll
        for(int r=0;r<4;r++){
          int ml = rbase + i*16 + g*4 + r;
          int nl = cbase + j*16 + l16;
          SM[nl*136 + ml] = f2b(acc[i][j][r]);
        }
    __syncthreads();
    int bb = m0 >> 11;
    #pragma unroll
    for(int kk=0;kk<8;kk++){
      int id = t + 256*kk;
      int row = id>>4, ch = id&15;
      uint4 v = *(const uint4*)&SM[row*136 + ch*8];
      int n = n0 + row;
      size_t dst = ((size_t)(bb*16 + (n>>6))*64 + (n&63))*2048 + (m0&2047) + ch*8;
      *(uint4*)&vt[dst] = v;
    }
  } else {
    #pragma unroll
    for(int i=0;i<4;i++)
      #pragma unroll
      for(int j=0;j<4;j++)
        #pragma unroll
        for(int r=0;r<4;r++){
          int m = m0 + rbase + i*16 + g*4 + r;
          int n = n0 + cbase + j*16 + l16;
          float v = acc[i][j][r];
          if(z==0) v *= LOG2E;
          int b = m >> 11, s = m & 2047;
          int hh = n >> 6, d = n & 63;
          size_t a = ((size_t)(b*16+hh)*2048 + s)*64 + d;
          u16 hb = f2b(v);
          if(z==0){ qh[a]=hb; ql[a]=f2b(v - b2f(hb)); }
          else    { kh[a]=hb; }
        }
  }
}

// ---------------- flash attention (split-K x2, BARRIER-FREE: K/V direct to VGPR) ----------------
__global__ __launch_bounds__(256) void k_attn(const u16* __restrict__ qh, const u16* __restrict__ ql,
                                              const u16* __restrict__ kh,
                                              const u16* __restrict__ vt, const float* __restrict__ bt2,
                                              const float* __restrict__ msk2,
                                              float* __restrict__ Op, float* __restrict__ rsp){
  __shared__ __align__(16) u16 PS[4*2304];   // wave-private P relayout, stride 72
  int bh = blockIdx.y, b = bh>>4, h = bh&15;
  int q0 = blockIdx.x*128;
  int kha = blockIdx.z;
  int t = threadIdx.x, w = t>>6, lane = t&63, l16 = lane&15, g = lane>>4;
  size_t base  = (size_t)bh*2048*64;   // q/k: [bh][s][64]
  size_t vbase = (size_t)bh*64*2048;   // v^T: [bh][d][s]
  u16* PSw = PS + w*2304;
  const float* bt2h = bt2 + h*4096;
  const float* msk2b = msk2 + b*2048;

  // register-resident Q (pre-scaled by log2e)
  bf16x8 qfh[2][2], qfl[2][2];
  #pragma unroll
  for(int i=0;i<2;i++){
    int qr = q0 + w*32 + i*16 + l16;
    size_t a0 = base + (size_t)qr*64 + g*8;
    qfh[i][0] = *(const bf16x8*)&qh[a0];
    qfl[i][0] = *(const bf16x8*)&ql[a0];
    qfh[i][1] = *(const bf16x8*)&qh[a0+32];
    qfl[i][1] = *(const bf16x8*)&ql[a0+32];
  }
  f32x4 O[2][4];
  float rs[2][4];
  #pragma unroll
  for(int i=0;i<2;i++){
    #pragma unroll
    for(int jd=0;jd<4;jd++) O[i][jd] = {0.f,0.f,0.f,0.f};
    #pragma unroll
    for(int r=0;r<4;r++) rs[i][r] = 0.f;
  }

  const u16* krow0 = kh + base + (size_t)l16*64 + g*8;      // + (k0+j*16)*64
  const u16* vrow0 = vt + vbase + (size_t)l16*2048 + g*8;   // + jd*16*2048 + k0 + ds*32

  int kend = kha*1024 + 1024;
  for(int k0=kha*1024; k0<kend; k0+=64){
    // bias + mask C-init
    float mkj[4];
    #pragma unroll
    for(int j=0;j<4;j++) mkj[j] = msk2b[k0 + j*16 + l16];
    f32x4 sc[2][4];
    #pragma unroll
    for(int i=0;i<2;i++){
      const float* bb = bt2h + (k0 + l16 + 2047 - (q0 + w*32 + i*16 + g*4));
      #pragma unroll
      for(int j=0;j<4;j++){
        #pragma unroll
        for(int r=0;r<4;r++)
          sc[i][j][r] = bb[j*16 - r] + mkj[j];
      }
    }
    // QK^T: K frags straight from global (L2-warm), 2-term Q split
    #pragma unroll
    for(int j=0;j<4;j++){
      const u16* kr = krow0 + (size_t)(k0 + j*16)*64;
      bf16x8 kfh0 = *(const bf16x8*)kr;
      bf16x8 kfh1 = *(const bf16x8*)(kr + 32);
      #pragma unroll
      for(int i=0;i<2;i++){
        f32x4 s = sc[i][j];
        s = mfma16(qfh[i][0], kfh0, s);
        s = mfma16(qfl[i][0], kfh0, s);
        s = mfma16(qfh[i][1], kfh1, s);
        s = mfma16(qfl[i][1], kfh1, s);
        sc[i][j] = s;
      }
    }
    // exp2, accumulate l, write P to wave-private LDS
    #pragma unroll
    for(int i=0;i<2;i++){
      #pragma unroll
      for(int j=0;j<4;j++){
        #pragma unroll
        for(int r=0;r<4;r++){
          float p = fexp2(sc[i][j][r]);
          rs[i][r] += p;
          PSw[(i*16 + g*4 + r)*72 + j*16 + l16] = f2b(p);
        }
      }
    }
    // PV: V^T frags straight from global
    #pragma unroll
    for(int ds=0; ds<2; ds++){
      bf16x8 pa0 = *(const bf16x8*)&PSw[(     l16)*72 + ds*32 + g*8];
      bf16x8 pa1 = *(const bf16x8*)&PSw[(16 + l16)*72 + ds*32 + g*8];
      #pragma unroll
      for(int jd=0;jd<4;jd++){
        bf16x8 vb = *(const bf16x8*)(vrow0 + (size_t)(jd*16)*2048 + k0 + ds*32);
        O[0][jd] = mfma16(pa0, vb, O[0][jd]);
        O[1][jd] = mfma16(pa1, vb, O[1][jd]);
      }
    }
  }
  // epilogue: reduce rs within 16-lane groups, store fp32 partials
  size_t pbase = ((size_t)kha*32 + bh)*2048;
  #pragma unroll
  for(int i=0;i<2;i++){
    #pragma unroll
    for(int r=0;r<4;r++){
      float v = rs[i][r];
      v += __shfl_xor(v,1,64);
      v += __shfl_xor(v,2,64);
      v += __shfl_xor(v,4,64);
      v += __shfl_xor(v,8,64);
      int q = q0 + w*32 + i*16 + g*4 + r;
      size_t oo = (pbase + q)*64;
      #pragma unroll
      for(int jd=0;jd<4;jd++)
        Op[oo + jd*16 + l16] = O[i][jd][r];
      if(l16==0) rsp[pbase + q] = v;
    }
  }
}

// ---------------- split-K combine ----------------
__global__ __launch_bounds__(256) void k_combine(const float* __restrict__ Op, const float* __restrict__ rsp,
                                                 u16* __restrict__ ao){
  size_t fid = ((size_t)blockIdx.x*256 + threadIdx.x)*4;
  int m = (int)(fid >> 10), n = (int)(fid & 1023);
  int bh = (m>>11)*16 + (n>>6);
  int q = m & 2047, d = n & 63;
  size_t po = ((size_t)bh*2048 + q)*64 + d;
  f32x4 a = *(const f32x4*)&Op[po];
  f32x4 c = *(const f32x4*)&Op[po + 4194304];
  float inv = 1.f/(rsp[bh*2048 + q] + rsp[bh*2048 + q + 65536]);
  ushort4 o;
  o.x = f2b((a[0]+c[0])*inv);
  o.y = f2b((a[1]+c[1])*inv);
  o.z = f2b((a[2]+c[2])*inv);
  o.w = f2b((a[3]+c[3])*inv);
  *(ushort4*)&ao[fid] = o;
}

// ---------------- output projection ----------------
__global__ __launch_bounds__(256) void k_gemm_out(const u16* __restrict__ ao, const u16* __restrict__ wot,
                                                  float* __restrict__ out){
  __shared__ __align__(16) u16 SM[8192];
  u16* As = SM; u16* Bs = SM+4096;
  int m0 = blockIdx.y*128, n0 = blockIdx.x*128;
  int t = threadIdx.x, w = t>>6, lane = t&63, l16 = lane&15, g = lane>>4;
  f32x4 acc[4][4];
  #pragma unroll
  for(int i=0;i<4;i++)
    #pragma unroll
    for(int j=0;j<4;j++) acc[i][j] = {0.f,0.f,0.f,0.f};
  int rbase = (w>>1)*64, cbase = (w&1)*64;
  for(int k0=0;k0<1024;k0+=32){
    __syncthreads();
    #pragma unroll
    for(int jj=0;jj<4;jj++){
      int q = w + 4*jj;
      int arr = q>>3, sub = q&7;
      int row = sub*16 + (lane>>2);
      int lch = (lane&3) ^ ((row>>1)&3);
      const u16* src;
      if(arr==0) src = ao  + (size_t)(m0+row)*1024 + k0 + lch*8;
      else       src = wot + (size_t)(n0+row)*1024 + k0 + lch*8;
      gld16(src, &SM[q*512]);
    }
    __syncthreads();
    bf16x8 af[4];
    #pragma unroll
    for(int i=0;i<4;i++) af[i] = ldsA32(As, rbase + i*16 + l16, g);
    #pragma unroll
    for(int j=0;j<4;j++){
      bf16x8 bfb = ldsA32(Bs, cbase + j*16 + l16, g);
      #pragma unroll
      for(int i=0;i<4;i++)
        acc[i][j] = mfma16(af[i], bfb, acc[i][j]);
    }
  }
  #pragma unroll
  for(int i=0;i<4;i++)
    #pragma unroll
    for(int j=0;j<4;j++)
      #pragma unroll
      for(int r=0;r<4;r++){
        int m = m0 + rbase + i*16 + g*4 + r;
        int n = n0 + cbase + j*16 + l16;
        out[(size_t)m*1024 + n] = acc[i][j][r];
      }
}

// ---------------- launch ----------------
extern "C" void kernel_launch(void* const* d_in, const int* in_sizes, int n_in,
                              void* d_out, int out_size, void* d_ws, size_t ws_size,
                              hipStream_t stream) {
  const float* x   = (const float*)d_in[0];
  const float* Wq  = (const float*)d_in[1];
  const float* Wk  = (const float*)d_in[2];
  const float* Wv  = (const float*)d_in[3];
  const float* Wo  = (const float*)d_in[4];
  const float* rel = (const float*)d_in[5];
  const float* msk = (const float*)d_in[6];
  float* out = (float*)d_out;
  float* bias_out = out + (size_t)4194304;
  char* ws = (char*)d_ws;
  u16* xh  = (u16*)(ws + 0);              // 8 MB
  u16* xl  = (u16*)(ws + 8388608);        // 8 MB
  u16* wth = (u16*)(ws + 16777216);       // 6 MB
  u16* wot = (u16*)(ws + 23068672);       // 2 MB
  u16* qh  = (u16*)(ws + 25165824);       // 8 MB
  u16* ql  = (u16*)(ws + 33554432);       // 8 MB
  u16* kh  = (u16*)(ws + 41943040);       // 8 MB
  u16* vt  = (u16*)(ws + 50331648);       // 8 MB (32 x 64 x 2048)
  u16* ao  = (u16*)(ws + 58720256);       // 8 MB
  float* Op  = (float*)(ws + 67108864);   // 32 MB (2 halves x 16 MB)
  float* rsp = (float*)(ws + 100663296);  // 512 KB
  float* bt  = (float*)(ws + 101187584);  // 256 KB
  float* bt2 = (float*)(ws + 101449728);  // 256 KB
  float* msk2= (float*)(ws + 101711872);  // 16 KB

  k_convert_x <<<4096, 256, 0, stream>>>(x, xh, xl);
  k_convert_w <<<dim3(16,16,4), 256, 0, stream>>>(Wq, Wk, Wv, Wo, wth, wot);
  k_bias_table<<<256, 256, 0, stream>>>(rel, msk, bt, bt2, msk2);
  k_write_bias<<<65536, 256, 0, stream>>>(bt, bias_out);
  k_gemm_qkv  <<<dim3(8,32,3), 256, 0, stream>>>(xh, xl, wth, qh, ql, kh, vt);
  k_attn      <<<dim3(16,32,2), 256, 0, stream>>>(qh, ql, kh, vt, bt2, msk2, Op, rsp);
  k_combine   <<<4096, 256, 0, stream>>>(Op, rsp, ao);
  k_gemm_out  <<<dim3(8,32), 256, 0, stream>>>(ao, wot, out);
}

// Round 7
// 516.269 us; speedup vs baseline: 1.2257x; 1.2257x over previous
//
#include <hip/hip_runtime.h>
#include <hip/hip_bf16.h>
#include <math.h>
#include <stdint.h>

typedef __bf16 bf16_t;
typedef __attribute__((ext_vector_type(8))) __bf16 bf16x8;
typedef __attribute__((ext_vector_type(4))) float f32x4;
typedef unsigned short u16;
typedef unsigned int u32;

#define DEV static __device__ __forceinline__
#define LOG2E 1.4426950408889634f

DEV u16 f2b(float f){ bf16_t h = (bf16_t)f; return __builtin_bit_cast(u16, h); }
DEV float b2f(u16 u){ bf16_t h = __builtin_bit_cast(bf16_t, u); return (float)h; }
DEV f32x4 mfma16(bf16x8 a, bf16x8 b, f32x4 c){
  return __builtin_amdgcn_mfma_f32_16x16x32_bf16(a, b, c, 0, 0, 0);
}

#if __has_builtin(__builtin_amdgcn_exp2f)
DEV float fexp2(float x){ return __builtin_amdgcn_exp2f(x); }
#else
DEV float fexp2(float x){ return exp2f(x); }
#endif

DEV void gld16(const void* g, void* l){
  __builtin_amdgcn_global_load_lds((const __attribute__((address_space(1))) u32*)g,
                                   (__attribute__((address_space(3))) u32*)l, 16, 0, 0);
}

DEV bf16x8 ldsA64(const u16* arr, int row, int ch){
  return *(const bf16x8*)&arr[row*64 + ((ch ^ (row&7))*8)];
}
DEV bf16x8 ldsA32(const u16* arr, int row, int ch){
  return *(const bf16x8*)&arr[row*32 + ((ch ^ ((row>>1)&3))*8)];
}

// ---------------- merged prep: convert_x (blocks 0..4095) + convert_w (4096..5119) + bias_table (5120..5375) ----------------
__global__ __launch_bounds__(256) void k_prep(const float* __restrict__ x,
                                              const float* __restrict__ Wq, const float* __restrict__ Wk,
                                              const float* __restrict__ Wv, const float* __restrict__ Wo,
                                              const float* __restrict__ rel_table, const float* __restrict__ mask,
                                              u16* __restrict__ xh, u16* __restrict__ xl,
                                              u16* __restrict__ wth, u16* __restrict__ wot,
                                              float* __restrict__ bt, float* __restrict__ bt2,
                                              float* __restrict__ msk2){
  __shared__ float tile[64][65];
  int bid = blockIdx.x;
  int t = threadIdx.x;
  if(bid < 4096){
    // split x into bf16 hi+lo
    size_t i = ((size_t)bid*256 + t)*4;
    float4 v = *(const float4*)(x + i);
    ushort4 hv, lv; float f, hf;
    f=v.x; hv.x=f2b(f); hf=b2f(hv.x); lv.x=f2b(f-hf);
    f=v.y; hv.y=f2b(f); hf=b2f(hv.y); lv.y=f2b(f-hf);
    f=v.z; hv.z=f2b(f); hf=b2f(hv.z); lv.z=f2b(f-hf);
    f=v.w; hv.w=f2b(f); hf=b2f(hv.w); lv.w=f2b(f-hf);
    *(ushort4*)(xh+i) = hv;
    *(ushort4*)(xl+i) = lv;
  } else if(bid < 5120){
    // transpose W [K][N] -> Wt [N][K], bf16 hi
    int rr = bid - 4096;
    int z = rr >> 8, ky = (rr >> 4) & 15, nx = rr & 15;
    const float* W = (z==0)?Wq:((z==1)?Wk:((z==2)?Wv:Wo));
    int n0 = nx*64, k0 = ky*64;
    int r = t>>6, c = t&63;
    #pragma unroll
    for(int i=0;i<16;i++){
      int row = i*4 + r;
      tile[row][c] = W[(size_t)(k0+row)*1024 + n0 + c];
    }
    __syncthreads();
    #pragma unroll
    for(int i=0;i<16;i++){
      int nrow = i*4 + r;
      float v = tile[c][nrow];
      size_t o = (size_t)(n0+nrow)*1024 + k0 + c;
      if(z<3) wth[(size_t)z*1048576 + o] = f2b(v);
      else    wot[o] = f2b(v);
    }
  } else {
    int gid = (bid-5120)*256 + t;   // 16*4096
    if(gid < 4096) msk2[gid] = mask[gid]*LOG2E;
    int h = gid >> 12, idx = gid & 4095;
    float v = 0.f;
    if(idx < 4095){
      int delta = idx - 2047;   // k - q
      int n = -delta;
      int ret = 0;
      if(n < 0){ ret = 16; n = -n; }
      int bucket;
      if(n < 8) bucket = n + ret;
      else {
        float a = (float)log((double)n * 0.125);
        float rr2 = (float)((double)a / (double)2.7725887298583984f);
        int vl = 8 + (int)(rr2 * 8.0f);
        vl = vl > 15 ? 15 : vl;
        bucket = vl + ret;
      }
      v = rel_table[bucket*16 + h];
    }
    bt[gid] = v;
    bt2[gid] = v*LOG2E - 32.0f;
  }
}

__global__ __launch_bounds__(256) void k_write_bias(const float* __restrict__ bt,
                                                    float* __restrict__ out){
  size_t f = ((size_t)blockIdx.x*256 + threadIdx.x)*4;
  int h = (int)(f >> 22);
  int rem = (int)(f & 4194303);
  int q = rem >> 11;
  int k = rem & 2047;
  const float* row = bt + h*4096 + (k - q + 2047);
  float4 v = make_float4(row[0], row[1], row[2], row[3]);
  *(float4*)(out + f) = v;
}

// ---------------- QKV projection GEMM ----------------
// Q: 2-term ((xh+xl)*Wh); K,V: 1-term (xh*Wh)
__global__ __launch_bounds__(256) void k_gemm_qkv(const u16* __restrict__ xh, const u16* __restrict__ xl,
                                                  const u16* __restrict__ wth,
                                                  u16* __restrict__ qh, u16* __restrict__ ql,
                                                  u16* __restrict__ kh, u16* __restrict__ vt){
  __shared__ __align__(16) u16 SM[17408];
  u16* Ah = SM; u16* Al = SM+4096; u16* Bh = SM+8192;
  int z = blockIdx.z;
  const u16* WH = wth + (size_t)z*1048576;
  int m0 = blockIdx.y*128, n0 = blockIdx.x*128;
  int t = threadIdx.x, w = t>>6, lane = t&63, l16 = lane&15, g = lane>>4;
  f32x4 acc[4][4];
  #pragma unroll
  for(int i=0;i<4;i++)
    #pragma unroll
    for(int j=0;j<4;j++) acc[i][j] = {0.f,0.f,0.f,0.f};
  int rbase = (w>>1)*64, cbase = (w&1)*64;
  for(int k0=0;k0<1024;k0+=32){
    __syncthreads();
    #pragma unroll
    for(int jj=0;jj<6;jj++){
      int q = w + 4*jj;            // chunk id 0..23: Ah 0-7, Al 8-15, Bh 16-23
      int arr = q>>3, sub = q&7;
      if(z!=0 && arr==1) continue;      // K,V: single-term, skip x-lo
      int row = sub*16 + (lane>>2);
      int lch = (lane&3) ^ ((row>>1)&3);
      const u16* src;
      if(arr==0)      src = xh + (size_t)(m0+row)*1024 + k0 + lch*8;
      else if(arr==1) src = xl + (size_t)(m0+row)*1024 + k0 + lch*8;
      else            src = WH + (size_t)(n0+row)*1024 + k0 + lch*8;
      gld16(src, &SM[q*512]);
    }
    __syncthreads();
    if(z!=0){
      bf16x8 ah[4];
      #pragma unroll
      for(int i=0;i<4;i++) ah[i] = ldsA32(Ah, rbase + i*16 + l16, g);
      #pragma unroll
      for(int j=0;j<4;j++){
        bf16x8 bh = ldsA32(Bh, cbase + j*16 + l16, g);
        #pragma unroll
        for(int i=0;i<4;i++)
          acc[i][j] = mfma16(ah[i], bh, acc[i][j]);
      }
    } else {
      bf16x8 ah[4], am[4];
      #pragma unroll
      for(int i=0;i<4;i++){
        int row = rbase + i*16 + l16;
        ah[i] = ldsA32(Ah, row, g);
        am[i] = ldsA32(Al, row, g);
      }
      #pragma unroll
      for(int j=0;j<4;j++){
        bf16x8 bh = ldsA32(Bh, cbase + j*16 + l16, g);
        #pragma unroll
        for(int i=0;i<4;i++){
          acc[i][j] = mfma16(ah[i], bh, acc[i][j]);
          acc[i][j] = mfma16(am[i], bh, acc[i][j]);
        }
      }
    }
  }
  if(z==2){
    // V: transpose via LDS (stride 136), coalesced 16B stores; vt [bh][d][s]
    __syncthreads();
    #pragma unroll
    for(int i=0;i<4;i++)
      #pragma unroll
      for(int j=0;j<4;j++)
        #pragma unroll
        for(int r=0;r<4;r++){
          int ml = rbase + i*16 + g*4 + r;
          int nl = cbase + j*16 + l16;
          SM[nl*136 + ml] = f2b(acc[i][j][r]);
        }
    __syncthreads();
    int bb = m0 >> 11;
    #pragma unroll
    for(int kk=0;kk<8;kk++){
      int id = t + 256*kk;
      int row = id>>4, ch = id&15;
      uint4 v = *(const uint4*)&SM[row*136 + ch*8];
      int n = n0 + row;
      size_t dst = ((size_t)(bb*16 + (n>>6))*64 + (n&63))*2048 + (m0&2047) + ch*8;
      *(uint4*)&vt[dst] = v;
    }
  } else {
    #pragma unroll
    for(int i=0;i<4;i++)
      #pragma unroll
      for(int j=0;j<4;j++)
        #pragma unroll
        for(int r=0;r<4;r++){
          int m = m0 + rbase + i*16 + g*4 + r;
          int n = n0 + cbase + j*16 + l16;
          float v = acc[i][j][r];
          if(z==0) v *= LOG2E;
          int b = m >> 11, s = m & 2047;
          int hh = n >> 6, d = n & 63;
          size_t a = ((size_t)(b*16+hh)*2048 + s)*64 + d;
          u16 hb = f2b(v);
          if(z==0){ qh[a]=hb; ql[a]=f2b(v - b2f(hb)); }
          else    { kh[a]=hb; }
        }
  }
}

// ---------------- flash attention (split-K x2, LDS-staged, R5-proven) ----------------
__global__ __launch_bounds__(256) void k_attn(const u16* __restrict__ qh, const u16* __restrict__ ql,
                                              const u16* __restrict__ kh,
                                              const u16* __restrict__ vt, const float* __restrict__ bt2,
                                              const float* __restrict__ msk2,
                                              float* __restrict__ Op, float* __restrict__ rsp){
  // KH[0..4096) VT[4096..8192) PS[8192..17408) (4 waves x 32x72)
  __shared__ __align__(16) u16 SM[17408];
  u16* KH = SM; u16* VT = SM+4096;
  int bh = blockIdx.y, b = bh>>4, h = bh&15;
  int q0 = blockIdx.x*128;
  int kha = blockIdx.z;
  int t = threadIdx.x, w = t>>6, lane = t&63, l16 = lane&15, g = lane>>4;
  size_t base  = (size_t)bh*2048*64;   // q/k: [bh][s][64]
  size_t vbase = (size_t)bh*64*2048;   // v^T: [bh][d][s]
  u16* PSw = SM + 8192 + w*2304;
  const float* bt2h = bt2 + h*4096;
  const float* msk2b = msk2 + b*2048;

  // register-resident Q (pre-scaled by log2e)
  bf16x8 qfh[2][2], qfl[2][2];
  #pragma unroll
  for(int i=0;i<2;i++){
    int qr = q0 + w*32 + i*16 + l16;
    size_t a0 = base + (size_t)qr*64 + g*8;
    qfh[i][0] = *(const bf16x8*)&qh[a0];
    qfl[i][0] = *(const bf16x8*)&ql[a0];
    qfh[i][1] = *(const bf16x8*)&qh[a0+32];
    qfl[i][1] = *(const bf16x8*)&ql[a0+32];
  }
  f32x4 O[2][4];
  float rs[2][4];
  #pragma unroll
  for(int i=0;i<2;i++){
    #pragma unroll
    for(int jd=0;jd<4;jd++) O[i][jd] = {0.f,0.f,0.f,0.f};
    #pragma unroll
    for(int r=0;r<4;r++) rs[i][r] = 0.f;
  }

  int kend = kha*1024 + 1024;
  for(int k0=kha*1024; k0<kend; k0+=64){
    __syncthreads();
    // stage KH/VT: 16 x 1KB DMA chunks, 4 per wave
    #pragma unroll
    for(int jj=0;jj<4;jj++){
      int q = w + 4*jj;
      int arr = q>>3, sub = q&7;
      int row = sub*8 + (lane>>3);
      int lch = (lane&7) ^ (row&7);
      const u16* src;
      if(arr==0) src = kh + base + (size_t)(k0+row)*64 + lch*8;
      else       src = vt + vbase + (size_t)row*2048 + k0 + lch*8;
      gld16(src, &SM[q*512]);
    }
    // init acc with bias+mask (loads overlap the DMA wait)
    float mkj[4];
    #pragma unroll
    for(int j=0;j<4;j++) mkj[j] = msk2b[k0 + j*16 + l16];
    f32x4 sc[2][4];
    #pragma unroll
    for(int i=0;i<2;i++){
      const float* bb = bt2h + (k0 + l16 + 2047 - (q0 + w*32 + i*16 + g*4));
      #pragma unroll
      for(int j=0;j<4;j++){
        #pragma unroll
        for(int r=0;r<4;r++)
          sc[i][j][r] = bb[j*16 - r] + mkj[j];
      }
    }
    __syncthreads();
    // QK^T, 2-term split (qh+ql vs kh)
    #pragma unroll
    for(int j=0;j<4;j++){
      int krow = j*16 + l16;
      bf16x8 kfh0 = ldsA64(KH, krow, g);
      bf16x8 kfh1 = ldsA64(KH, krow, 4+g);
      #pragma unroll
      for(int i=0;i<2;i++){
        f32x4 s = sc[i][j];
        s = mfma16(qfh[i][0], kfh0, s);
        s = mfma16(qfl[i][0], kfh0, s);
        s = mfma16(qfh[i][1], kfh1, s);
        s = mfma16(qfl[i][1], kfh1, s);
        sc[i][j] = s;
      }
    }
    // exp2, accumulate l, write P to LDS
    #pragma unroll
    for(int i=0;i<2;i++){
      #pragma unroll
      for(int j=0;j<4;j++){
        #pragma unroll
        for(int r=0;r<4;r++){
          float p = fexp2(sc[i][j][r]);
          rs[i][r] += p;
          PSw[(i*16 + g*4 + r)*72 + j*16 + l16] = f2b(p);
        }
      }
    }
    // PV (PS is wave-private, no barrier)
    #pragma unroll
    for(int ds=0; ds<2; ds++){
      bf16x8 pa0 = *(const bf16x8*)&PSw[(     l16)*72 + ds*32 + g*8];
      bf16x8 pa1 = *(const bf16x8*)&PSw[(16 + l16)*72 + ds*32 + g*8];
      #pragma unroll
      for(int jd=0;jd<4;jd++){
        bf16x8 vb = ldsA64(VT, jd*16 + l16, ds*4 + g);
        O[0][jd] = mfma16(pa0, vb, O[0][jd]);
        O[1][jd] = mfma16(pa1, vb, O[1][jd]);
      }
    }
  }
  // epilogue: reduce rs within 16-lane groups, store fp32 partials
  size_t pbase = ((size_t)kha*32 + bh)*2048;
  #pragma unroll
  for(int i=0;i<2;i++){
    #pragma unroll
    for(int r=0;r<4;r++){
      float v = rs[i][r];
      v += __shfl_xor(v,1,64);
      v += __shfl_xor(v,2,64);
      v += __shfl_xor(v,4,64);
      v += __shfl_xor(v,8,64);
      int q = q0 + w*32 + i*16 + g*4 + r;
      size_t oo = (pbase + q)*64;
      #pragma unroll
      for(int jd=0;jd<4;jd++)
        Op[oo + jd*16 + l16] = O[i][jd][r];
      if(l16==0) rsp[pbase + q] = v;
    }
  }
}

// ---------------- split-K combine ----------------
__global__ __launch_bounds__(256) void k_combine(const float* __restrict__ Op, const float* __restrict__ rsp,
                                                 u16* __restrict__ ao){
  size_t fid = ((size_t)blockIdx.x*256 + threadIdx.x)*4;
  int m = (int)(fid >> 10), n = (int)(fid & 1023);
  int bh = (m>>11)*16 + (n>>6);
  int q = m & 2047, d = n & 63;
  size_t po = ((size_t)bh*2048 + q)*64 + d;
  f32x4 a = *(const f32x4*)&Op[po];
  f32x4 c = *(const f32x4*)&Op[po + 4194304];
  float inv = 1.f/(rsp[bh*2048 + q] + rsp[bh*2048 + q + 65536]);
  ushort4 o;
  o.x = f2b((a[0]+c[0])*inv);
  o.y = f2b((a[1]+c[1])*inv);
  o.z = f2b((a[2]+c[2])*inv);
  o.w = f2b((a[3]+c[3])*inv);
  *(ushort4*)&ao[fid] = o;
}

// ---------------- output projection ----------------
__global__ __launch_bounds__(256) void k_gemm_out(const u16* __restrict__ ao, const u16* __restrict__ wot,
                                                  float* __restrict__ out){
  __shared__ __align__(16) u16 SM[8192];
  u16* As = SM; u16* Bs = SM+4096;
  int m0 = blockIdx.y*128, n0 = blockIdx.x*128;
  int t = threadIdx.x, w = t>>6, lane = t&63, l16 = lane&15, g = lane>>4;
  f32x4 acc[4][4];
  #pragma unroll
  for(int i=0;i<4;i++)
    #pragma unroll
    for(int j=0;j<4;j++) acc[i][j] = {0.f,0.f,0.f,0.f};
  int rbase = (w>>1)*64, cbase = (w&1)*64;
  for(int k0=0;k0<1024;k0+=32){
    __syncthreads();
    #pragma unroll
    for(int jj=0;jj<4;jj++){
      int q = w + 4*jj;
      int arr = q>>3, sub = q&7;
      int row = sub*16 + (lane>>2);
      int lch = (lane&3) ^ ((row>>1)&3);
      const u16* src;
      if(arr==0) src = ao  + (size_t)(m0+row)*1024 + k0 + lch*8;
      else       src = wot + (size_t)(n0+row)*1024 + k0 + lch*8;
      gld16(src, &SM[q*512]);
    }
    __syncthreads();
    bf16x8 af[4];
    #pragma unroll
    for(int i=0;i<4;i++) af[i] = ldsA32(As, rbase + i*16 + l16, g);
    #pragma unroll
    for(int j=0;j<4;j++){
      bf16x8 bfb = ldsA32(Bs, cbase + j*16 + l16, g);
      #pragma unroll
      for(int i=0;i<4;i++)
        acc[i][j] = mfma16(af[i], bfb, acc[i][j]);
    }
  }
  #pragma unroll
  for(int i=0;i<4;i++)
    #pragma unroll
    for(int j=0;j<4;j++)
      #pragma unroll
      for(int r=0;r<4;r++){
        int m = m0 + rbase + i*16 + g*4 + r;
        int n = n0 + cbase + j*16 + l16;
        out[(size_t)m*1024 + n] = acc[i][j][r];
      }
}

// ---------------- launch ----------------
extern "C" void kernel_launch(void* const* d_in, const int* in_sizes, int n_in,
                              void* d_out, int out_size, void* d_ws, size_t ws_size,
                              hipStream_t stream) {
  const float* x   = (const float*)d_in[0];
  const float* Wq  = (const float*)d_in[1];
  const float* Wk  = (const float*)d_in[2];
  const float* Wv  = (const float*)d_in[3];
  const float* Wo  = (const float*)d_in[4];
  const float* rel = (const float*)d_in[5];
  const float* msk = (const float*)d_in[6];
  float* out = (float*)d_out;
  float* bias_out = out + (size_t)4194304;
  char* ws = (char*)d_ws;
  u16* xh  = (u16*)(ws + 0);              // 8 MB
  u16* xl  = (u16*)(ws + 8388608);        // 8 MB
  u16* wth = (u16*)(ws + 16777216);       // 6 MB
  u16* wot = (u16*)(ws + 23068672);       // 2 MB
  u16* qh  = (u16*)(ws + 25165824);       // 8 MB
  u16* ql  = (u16*)(ws + 33554432);       // 8 MB
  u16* kh  = (u16*)(ws + 41943040);       // 8 MB
  u16* vt  = (u16*)(ws + 50331648);       // 8 MB (32 x 64 x 2048)
  u16* ao  = (u16*)(ws + 58720256);       // 8 MB
  float* Op  = (float*)(ws + 67108864);   // 32 MB (2 halves x 16 MB)
  float* rsp = (float*)(ws + 100663296);  // 512 KB
  float* bt  = (float*)(ws + 101187584);  // 256 KB
  float* bt2 = (float*)(ws + 101449728);  // 256 KB
  float* msk2= (float*)(ws + 101711872);  // 16 KB

  k_prep      <<<5376, 256, 0, stream>>>(x, Wq, Wk, Wv, Wo, rel, msk,
                                         xh, xl, wth, wot, bt, bt2, msk2);
  k_write_bias<<<65536, 256, 0, stream>>>(bt, bias_out);
  k_gemm_qkv  <<<dim3(8,32,3), 256, 0, stream>>>(xh, xl, wth, qh, ql, kh, vt);
  k_attn      <<<dim3(16,32,2), 256, 0, stream>>>(qh, ql, kh, vt, bt2, msk2, Op, rsp);
  k_combine   <<<4096, 256, 0, stream>>>(Op, rsp, ao);
  k_gemm_out  <<<dim3(8,32), 256, 0, stream>>>(ao, wot, out);
}

// Round 8
// 508.969 us; speedup vs baseline: 1.2433x; 1.0143x over previous
//
#include <hip/hip_runtime.h>
#include <hip/hip_bf16.h>
#include <math.h>
#include <stdint.h>

typedef __bf16 bf16_t;
typedef __attribute__((ext_vector_type(8))) __bf16 bf16x8;
typedef __attribute__((ext_vector_type(4))) float f32x4;
typedef float f32x4a __attribute__((ext_vector_type(4), aligned(4)));
typedef unsigned short u16;
typedef unsigned int u32;

#define DEV static __device__ __forceinline__
#define LOG2E 1.4426950408889634f

DEV u16 f2b(float f){ bf16_t h = (bf16_t)f; return __builtin_bit_cast(u16, h); }
DEV float b2f(u16 u){ bf16_t h = __builtin_bit_cast(bf16_t, u); return (float)h; }
DEV f32x4 mfma16(bf16x8 a, bf16x8 b, f32x4 c){
  return __builtin_amdgcn_mfma_f32_16x16x32_bf16(a, b, c, 0, 0, 0);
}

#if __has_builtin(__builtin_amdgcn_exp2f)
DEV float fexp2(float x){ return __builtin_amdgcn_exp2f(x); }
#else
DEV float fexp2(float x){ return exp2f(x); }
#endif

DEV void gld16(const void* g, void* l){
  __builtin_amdgcn_global_load_lds((const __attribute__((address_space(1))) u32*)g,
                                   (__attribute__((address_space(3))) u32*)l, 16, 0, 0);
}

DEV bf16x8 ldsA64(const u16* arr, int row, int ch){
  return *(const bf16x8*)&arr[row*64 + ((ch ^ (row&7))*8)];
}
DEV bf16x8 ldsA32(const u16* arr, int row, int ch){
  return *(const bf16x8*)&arr[row*32 + ((ch ^ ((row>>1)&3))*8)];
}

// ---------------- merged prep: convert_x (blocks 0..4095) + convert_w (4096..5119) + bias_table (5120..5375) ----------------
__global__ __launch_bounds__(256) void k_prep(const float* __restrict__ x,
                                              const float* __restrict__ Wq, const float* __restrict__ Wk,
                                              const float* __restrict__ Wv, const float* __restrict__ Wo,
                                              const float* __restrict__ rel_table, const float* __restrict__ mask,
                                              u16* __restrict__ xh, u16* __restrict__ xl,
                                              u16* __restrict__ wth, u16* __restrict__ wot,
                                              float* __restrict__ bt, float* __restrict__ bt2,
                                              float* __restrict__ msk2){
  __shared__ float tile[64][65];
  int bid = blockIdx.x;
  int t = threadIdx.x;
  if(bid < 4096){
    size_t i = ((size_t)bid*256 + t)*4;
    float4 v = *(const float4*)(x + i);
    ushort4 hv, lv; float f, hf;
    f=v.x; hv.x=f2b(f); hf=b2f(hv.x); lv.x=f2b(f-hf);
    f=v.y; hv.y=f2b(f); hf=b2f(hv.y); lv.y=f2b(f-hf);
    f=v.z; hv.z=f2b(f); hf=b2f(hv.z); lv.z=f2b(f-hf);
    f=v.w; hv.w=f2b(f); hf=b2f(hv.w); lv.w=f2b(f-hf);
    *(ushort4*)(xh+i) = hv;
    *(ushort4*)(xl+i) = lv;
  } else if(bid < 5120){
    int rr = bid - 4096;
    int z = rr >> 8, ky = (rr >> 4) & 15, nx = rr & 15;
    const float* W = (z==0)?Wq:((z==1)?Wk:((z==2)?Wv:Wo));
    int n0 = nx*64, k0 = ky*64;
    int r = t>>6, c = t&63;
    #pragma unroll
    for(int i=0;i<16;i++){
      int row = i*4 + r;
      tile[row][c] = W[(size_t)(k0+row)*1024 + n0 + c];
    }
    __syncthreads();
    #pragma unroll
    for(int i=0;i<16;i++){
      int nrow = i*4 + r;
      float v = tile[c][nrow];
      size_t o = (size_t)(n0+nrow)*1024 + k0 + c;
      if(z<3) wth[(size_t)z*1048576 + o] = f2b(v);
      else    wot[o] = f2b(v);
    }
  } else {
    int gid = (bid-5120)*256 + t;   // 16*4096
    if(gid < 4096) msk2[gid] = mask[gid]*LOG2E;
    int h = gid >> 12, idx = gid & 4095;
    float v = 0.f;
    if(idx < 4095){
      int delta = idx - 2047;   // k - q
      int n = -delta;
      int ret = 0;
      if(n < 0){ ret = 16; n = -n; }
      int bucket;
      if(n < 8) bucket = n + ret;
      else {
        float a = (float)log((double)n * 0.125);
        float rr2 = (float)((double)a / (double)2.7725887298583984f);
        int vl = 8 + (int)(rr2 * 8.0f);
        vl = vl > 15 ? 15 : vl;
        bucket = vl + ret;
      }
      v = rel_table[bucket*16 + h];
    }
    bt[gid] = v;
    bt2[gid] = v*LOG2E - 32.0f;
  }
}

__global__ __launch_bounds__(256) void k_write_bias(const float* __restrict__ bt,
                                                    float* __restrict__ out){
  size_t f = ((size_t)blockIdx.x*256 + threadIdx.x)*4;
  int h = (int)(f >> 22);
  int rem = (int)(f & 4194303);
  int q = rem >> 11;
  int k = rem & 2047;
  const float* row = bt + h*4096 + (k - q + 2047);
  float4 v = make_float4(row[0], row[1], row[2], row[3]);
  *(float4*)(out + f) = v;
}

// ---------------- QKV projection GEMM ----------------
// Q: 2-term ((xh+xl)*Wh); K,V: 1-term (xh*Wh)
__global__ __launch_bounds__(256) void k_gemm_qkv(const u16* __restrict__ xh, const u16* __restrict__ xl,
                                                  const u16* __restrict__ wth,
                                                  u16* __restrict__ qh, u16* __restrict__ ql,
                                                  u16* __restrict__ kh, u16* __restrict__ vt){
  __shared__ __align__(16) u16 SM[17408];
  u16* Ah = SM; u16* Al = SM+4096; u16* Bh = SM+8192;
  int z = blockIdx.z;
  const u16* WH = wth + (size_t)z*1048576;
  int m0 = blockIdx.y*128, n0 = blockIdx.x*128;
  int t = threadIdx.x, w = t>>6, lane = t&63, l16 = lane&15, g = lane>>4;
  f32x4 acc[4][4];
  #pragma unroll
  for(int i=0;i<4;i++)
    #pragma unroll
    for(int j=0;j<4;j++) acc[i][j] = {0.f,0.f,0.f,0.f};
  int rbase = (w>>1)*64, cbase = (w&1)*64;
  for(int k0=0;k0<1024;k0+=32){
    __syncthreads();
    #pragma unroll
    for(int jj=0;jj<6;jj++){
      int q = w + 4*jj;            // chunk id 0..23: Ah 0-7, Al 8-15, Bh 16-23
      int arr = q>>3, sub = q&7;
      if(z!=0 && arr==1) continue;      // K,V: single-term, skip x-lo
      int row = sub*16 + (lane>>2);
      int lch = (lane&3) ^ ((row>>1)&3);
      const u16* src;
      if(arr==0)      src = xh + (size_t)(m0+row)*1024 + k0 + lch*8;
      else if(arr==1) src = xl + (size_t)(m0+row)*1024 + k0 + lch*8;
      else            src = WH + (size_t)(n0+row)*1024 + k0 + lch*8;
      gld16(src, &SM[q*512]);
    }
    __syncthreads();
    if(z!=0){
      bf16x8 ah[4];
      #pragma unroll
      for(int i=0;i<4;i++) ah[i] = ldsA32(Ah, rbase + i*16 + l16, g);
      #pragma unroll
      for(int j=0;j<4;j++){
        bf16x8 bh = ldsA32(Bh, cbase + j*16 + l16, g);
        #pragma unroll
        for(int i=0;i<4;i++)
          acc[i][j] = mfma16(ah[i], bh, acc[i][j]);
      }
    } else {
      bf16x8 ah[4], am[4];
      #pragma unroll
      for(int i=0;i<4;i++){
        int row = rbase + i*16 + l16;
        ah[i] = ldsA32(Ah, row, g);
        am[i] = ldsA32(Al, row, g);
      }
      #pragma unroll
      for(int j=0;j<4;j++){
        bf16x8 bh = ldsA32(Bh, cbase + j*16 + l16, g);
        #pragma unroll
        for(int i=0;i<4;i++){
          acc[i][j] = mfma16(ah[i], bh, acc[i][j]);
          acc[i][j] = mfma16(am[i], bh, acc[i][j]);
        }
      }
    }
  }
  if(z==2){
    // V: transpose via LDS (stride 136), coalesced 16B stores; vt [bh][d][s]
    __syncthreads();
    #pragma unroll
    for(int i=0;i<4;i++)
      #pragma unroll
      for(int j=0;j<4;j++)
        #pragma unroll
        for(int r=0;r<4;r++){
          int ml = rbase + i*16 + g*4 + r;
          int nl = cbase + j*16 + l16;
          SM[nl*136 + ml] = f2b(acc[i][j][r]);
        }
    __syncthreads();
    int bb = m0 >> 11;
    #pragma unroll
    for(int kk=0;kk<8;kk++){
      int id = t + 256*kk;
      int row = id>>4, ch = id&15;
      uint4 v = *(const uint4*)&SM[row*136 + ch*8];
      int n = n0 + row;
      size_t dst = ((size_t)(bb*16 + (n>>6))*64 + (n&63))*2048 + (m0&2047) + ch*8;
      *(uint4*)&vt[dst] = v;
    }
  } else {
    #pragma unroll
    for(int i=0;i<4;i++)
      #pragma unroll
      for(int j=0;j<4;j++)
        #pragma unroll
        for(int r=0;r<4;r++){
          int m = m0 + rbase + i*16 + g*4 + r;
          int n = n0 + cbase + j*16 + l16;
          float v = acc[i][j][r];
          if(z==0) v *= LOG2E;
          int b = m >> 11, s = m & 2047;
          int hh = n >> 6, d = n & 63;
          size_t a = ((size_t)(b*16+hh)*2048 + s)*64 + d;
          u16 hb = f2b(v);
          if(z==0){ qh[a]=hb; ql[a]=f2b(v - b2f(hb)); }
          else    { kh[a]=hb; }
        }
  }
}

// ---------------- flash attention (q-tile 64, full-K, max-free exp2) ----------------
// LDS: KH[0,4096) VT[4096,8192) PS 4 waves x 16x72 [8192,12800)
__global__ __launch_bounds__(256) void k_attn(const u16* __restrict__ qh, const u16* __restrict__ ql,
                                              const u16* __restrict__ kh,
                                              const u16* __restrict__ vt, const float* __restrict__ bt2,
                                              const float* __restrict__ msk2,
                                              u16* __restrict__ ao){
  __shared__ __align__(16) u16 SM[12800];
  u16* KH = SM; u16* VT = SM+4096;
  int bh = blockIdx.y, b = bh>>4, h = bh&15;
  int q0 = blockIdx.x*64;
  int t = threadIdx.x, w = t>>6, lane = t&63, l16 = lane&15, g = lane>>4;
  size_t base  = (size_t)bh*2048*64;   // q/k: [bh][s][64]
  size_t vbase = (size_t)bh*64*2048;   // v^T: [bh][d][s]
  u16* PSw = SM + 8192 + w*1152;
  const float* bt2h = bt2 + h*4096;
  const float* msk2b = msk2 + b*2048;

  // register-resident Q (pre-scaled by log2e): wave w owns q-rows q0+w*16..+15
  bf16x8 qfh[2], qfl[2];
  {
    int qr = q0 + w*16 + l16;
    size_t a0 = base + (size_t)qr*64 + g*8;
    qfh[0] = *(const bf16x8*)&qh[a0];
    qfl[0] = *(const bf16x8*)&ql[a0];
    qfh[1] = *(const bf16x8*)&qh[a0+32];
    qfl[1] = *(const bf16x8*)&ql[a0+32];
  }
  f32x4 O[4];
  float rs[4];
  #pragma unroll
  for(int jd=0;jd<4;jd++) O[jd] = {0.f,0.f,0.f,0.f};
  #pragma unroll
  for(int r=0;r<4;r++) rs[r] = 0.f;
  int qgbase = q0 + w*16 + g*4;

  for(int k0=0;k0<2048;k0+=64){
    __syncthreads();
    // stage KH/VT: 16 x 1KB DMA chunks, 4 per wave
    #pragma unroll
    for(int jj=0;jj<4;jj++){
      int q = w + 4*jj;
      int arr = q>>3, sub = q&7;
      int row = sub*8 + (lane>>3);
      int lch = (lane&7) ^ (row&7);
      const u16* src;
      if(arr==0) src = kh + base + (size_t)(k0+row)*64 + lch*8;
      else       src = vt + vbase + (size_t)row*2048 + k0 + lch*8;
      gld16(src, &SM[q*512]);
    }
    // bias + mask C-init (vector loads, reversed in-register; overlaps DMA wait)
    f32x4 sc[4];
    {
      const float* bb = bt2h + (k0 + l16 + 2047 - qgbase);
      #pragma unroll
      for(int j=0;j<4;j++){
        f32x4a ld = *(const f32x4a*)(bb + j*16 - 3);
        float mk = msk2b[k0 + j*16 + l16];
        sc[j] = (f32x4){ld[3]+mk, ld[2]+mk, ld[1]+mk, ld[0]+mk};
      }
    }
    __syncthreads();
    // QK^T, 2-term split (qh+ql vs kh)
    #pragma unroll
    for(int j=0;j<4;j++){
      int krow = j*16 + l16;
      bf16x8 kfh0 = ldsA64(KH, krow, g);
      bf16x8 kfh1 = ldsA64(KH, krow, 4+g);
      f32x4 s = sc[j];
      s = mfma16(qfh[0], kfh0, s);
      s = mfma16(qfl[0], kfh0, s);
      s = mfma16(qfh[1], kfh1, s);
      s = mfma16(qfl[1], kfh1, s);
      sc[j] = s;
    }
    // exp2, accumulate l, write P to LDS
    #pragma unroll
    for(int j=0;j<4;j++){
      #pragma unroll
      for(int r=0;r<4;r++){
        float p = fexp2(sc[j][r]);
        rs[r] += p;
        PSw[(g*4+r)*72 + j*16 + l16] = f2b(p);
      }
    }
    // PV (PS is wave-private, no barrier)
    #pragma unroll
    for(int ds=0; ds<2; ds++){
      bf16x8 pa = *(const bf16x8*)&PSw[l16*72 + ds*32 + g*8];
      #pragma unroll
      for(int jd=0;jd<4;jd++){
        bf16x8 vb = ldsA64(VT, jd*16 + l16, ds*4 + g);
        O[jd] = mfma16(pa, vb, O[jd]);
      }
    }
  }
  // epilogue: reduce rs within 16-lane groups, normalize, store bf16
  #pragma unroll
  for(int r=0;r<4;r++){
    float v = rs[r];
    v += __shfl_xor(v,1,64);
    v += __shfl_xor(v,2,64);
    v += __shfl_xor(v,4,64);
    v += __shfl_xor(v,8,64);
    float inv = 1.f/v;
    int q = qgbase + r;
    size_t a = ((size_t)(b*2048 + q))*1024 + h*64;
    #pragma unroll
    for(int jd=0;jd<4;jd++)
      ao[a + jd*16 + l16] = f2b(O[jd][r]*inv);
  }
}

// ---------------- output projection ----------------
__global__ __launch_bounds__(256) void k_gemm_out(const u16* __restrict__ ao, const u16* __restrict__ wot,
                                                  float* __restrict__ out){
  __shared__ __align__(16) u16 SM[8192];
  u16* As = SM; u16* Bs = SM+4096;
  int m0 = blockIdx.y*128, n0 = blockIdx.x*128;
  int t = threadIdx.x, w = t>>6, lane = t&63, l16 = lane&15, g = lane>>4;
  f32x4 acc[4][4];
  #pragma unroll
  for(int i=0;i<4;i++)
    #pragma unroll
    for(int j=0;j<4;j++) acc[i][j] = {0.f,0.f,0.f,0.f};
  int rbase = (w>>1)*64, cbase = (w&1)*64;
  for(int k0=0;k0<1024;k0+=32){
    __syncthreads();
    #pragma unroll
    for(int jj=0;jj<4;jj++){
      int q = w + 4*jj;
      int arr = q>>3, sub = q&7;
      int row = sub*16 + (lane>>2);
      int lch = (lane&3) ^ ((row>>1)&3);
      const u16* src;
      if(arr==0) src = ao  + (size_t)(m0+row)*1024 + k0 + lch*8;
      else       src = wot + (size_t)(n0+row)*1024 + k0 + lch*8;
      gld16(src, &SM[q*512]);
    }
    __syncthreads();
    bf16x8 af[4];
    #pragma unroll
    for(int i=0;i<4;i++) af[i] = ldsA32(As, rbase + i*16 + l16, g);
    #pragma unroll
    for(int j=0;j<4;j++){
      bf16x8 bfb = ldsA32(Bs, cbase + j*16 + l16, g);
      #pragma unroll
      for(int i=0;i<4;i++)
        acc[i][j] = mfma16(af[i], bfb, acc[i][j]);
    }
  }
  #pragma unroll
  for(int i=0;i<4;i++)
    #pragma unroll
    for(int j=0;j<4;j++)
      #pragma unroll
      for(int r=0;r<4;r++){
        int m = m0 + rbase + i*16 + g*4 + r;
        int n = n0 + cbase + j*16 + l16;
        out[(size_t)m*1024 + n] = acc[i][j][r];
      }
}

// ---------------- launch ----------------
extern "C" void kernel_launch(void* const* d_in, const int* in_sizes, int n_in,
                              void* d_out, int out_size, void* d_ws, size_t ws_size,
                              hipStream_t stream) {
  const float* x   = (const float*)d_in[0];
  const float* Wq  = (const float*)d_in[1];
  const float* Wk  = (const float*)d_in[2];
  const float* Wv  = (const float*)d_in[3];
  const float* Wo  = (const float*)d_in[4];
  const float* rel = (const float*)d_in[5];
  const float* msk = (const float*)d_in[6];
  float* out = (float*)d_out;
  float* bias_out = out + (size_t)4194304;
  char* ws = (char*)d_ws;
  u16* xh  = (u16*)(ws + 0);              // 8 MB
  u16* xl  = (u16*)(ws + 8388608);        // 8 MB
  u16* wth = (u16*)(ws + 16777216);       // 6 MB
  u16* wot = (u16*)(ws + 23068672);       // 2 MB
  u16* qh  = (u16*)(ws + 25165824);       // 8 MB
  u16* ql  = (u16*)(ws + 33554432);       // 8 MB
  u16* kh  = (u16*)(ws + 41943040);       // 8 MB
  u16* vt  = (u16*)(ws + 50331648);       // 8 MB (32 x 64 x 2048)
  u16* ao  = (u16*)(ws + 58720256);       // 8 MB
  float* bt  = (float*)(ws + 67108864);   // 256 KB
  float* bt2 = (float*)(ws + 67371008);   // 256 KB
  float* msk2= (float*)(ws + 67633152);   // 16 KB

  k_prep      <<<5376, 256, 0, stream>>>(x, Wq, Wk, Wv, Wo, rel, msk,
                                         xh, xl, wth, wot, bt, bt2, msk2);
  k_write_bias<<<65536, 256, 0, stream>>>(bt, bias_out);
  k_gemm_qkv  <<<dim3(8,32,3), 256, 0, stream>>>(xh, xl, wth, qh, ql, kh, vt);
  k_attn      <<<dim3(32,32), 256, 0, stream>>>(qh, ql, kh, vt, bt2, msk2, ao);
  k_gemm_out  <<<dim3(8,32), 256, 0, stream>>>(ao, wot, out);
}